// Round 12
// baseline (117.790 us; speedup 1.0000x reference)
//
#include <hip/hip_runtime.h>
#include <hip/hip_bf16.h>
#include <math.h>

// B=4, C=384, H=W=Y=X=64, n_head=1, hd=32, P=4096
#define B_   4
#define C_   384
#define HD_  32
#define P_   4096
#define PADP 4356   // 66*66 padded pixel space
#define QSC_ 0.2550889266f   // (1/sqrt(32)) * log2(e), folded into Wq -> exp2 domain

typedef __attribute__((ext_vector_type(4))) float f32x4;
typedef __attribute__((ext_vector_type(8))) short short8;

static __device__ inline unsigned cvt_pk(float lo, float hi) {
    unsigned r;
    asm("v_cvt_pk_bf16_f32 %0, %1, %2" : "=v"(r) : "v"(lo), "v"(hi));
    return r;
}
static __device__ inline float exp2a(float x) {
    float r;
    asm("v_exp_f32 %0, %1" : "=v"(r) : "v"(x));
    return r;
}
static __device__ inline short bf16_bits(float a) {
    __hip_bfloat16 x = __float2bfloat16(a);
    return *reinterpret_cast<short*>(&x);
}

// ---- merged: weight repack + aoT border zero.
__global__ void repack_kernel(const float* __restrict__ Wq,
                              const float* __restrict__ Wkv,
                              const float* __restrict__ Wout,
                              short* __restrict__ Wball,
                              short* __restrict__ Wbc,
                              unsigned* __restrict__ aoT32) {
    int idx = blockIdx.x * 256 + threadIdx.x;
    if (idx < B_ * 260 * 16) {   // zero the 260 border pixels x 16 dwords
        int j = idx & 15;
        int p = (idx >> 4) % 260;
        int b = idx / (260 * 16);
        int hh, ww;
        if (p < 66)       { hh = 0;  ww = p; }
        else if (p < 132) { hh = 65; ww = p - 66; }
        else { int i = p - 132; hh = 1 + (i >> 1); ww = (i & 1) * 65; }
        aoT32[((size_t)b * PADP + hh * 66 + ww) * 16 + j] = 0;
    }
    if (idx < 96 * C_) {
        int r = idx / C_, c = idx % C_;
        float v = (r < 32) ? Wq[r * C_ + c] * QSC_ : Wkv[(r - 32) * C_ + c];
        Wball[idx] = bf16_bits(v);
    }
    int j = idx - 96 * C_;
    if (j >= 0 && j < 9 * 384 * 32) {
        int ci = j & 31;
        int co = (j >> 5) % 384;
        int kk = j / (384 * 32);
        int ky = kk / 3, kx = kk % 3;
        Wbc[j] = bf16_bits(Wout[((co * 32 + ci) * 3 + ky) * 3 + kx]);
    }
}

// ---- unified q/k/v projection from f32 inputs (R8 layouts).
__global__ __launch_bounds__(768)
void proj_kernel(const float* __restrict__ x, const float* __restrict__ xe,
                 const short* __restrict__ Wball,
                 short* __restrict__ qT, short* __restrict__ kT,
                 short* __restrict__ vT) {
    int b = blockIdx.y;
    int p0 = blockIdx.x << 5;
    int t = threadIdx.x, w = t >> 6, l = t & 63, lq = l & 15, h = l >> 4;
    int mt = w >> 1, pg = w & 1;
    int p = p0 + pg * 16 + lq;
    const float* in = (mt < 2) ? x : xe;
    const float* xb = in + (size_t)b * C_ * P_ + p;
    const short* Ap = Wball + (size_t)(mt * 16 + lq) * C_ + h * 8;
    f32x4 acc = {0.f, 0.f, 0.f, 0.f};
    for (int ks = 0; ks < 12; ++ks) {
        float xv[8];
        #pragma unroll
        for (int jj = 0; jj < 8; ++jj)
            xv[jj] = xb[(size_t)(ks * 32 + h * 8 + jj) * P_];
        unsigned u[4];
        #pragma unroll
        for (int jj = 0; jj < 4; ++jj) u[jj] = cvt_pk(xv[2 * jj], xv[2 * jj + 1]);
        short8 bf;
        __builtin_memcpy(&bf, u, 16);
        short8 af = *(const short8*)(Ap + ks * 32);
        acc = __builtin_amdgcn_mfma_f32_16x16x32_bf16(af, bf, acc, 0, 0, 0);
    }
    if (mt < 4) {
        short* dst = (mt < 2) ? qT : kT;
        int d = (mt & 1) * 16 + h * 4;
        uint2 u;
        u.x = cvt_pk(acc[0], acc[1]);
        u.y = cvt_pk(acc[2], acc[3]);
        *(uint2*)(dst + ((size_t)b * P_ + p) * HD_ + d) = u;
    } else {
        int d = (mt - 4) * 16 + h * 4;
        #pragma unroll
        for (int r = 0; r < 4; ++r)
            vT[((size_t)b * HD_ + d + r) * P_ + p] = bf16_bits(acc[r]);
    }
}

// ---- Flash attention (R8 body), fixed-max softmax, 32-q tiles, keys split across 2 blocks.
// grid B_*256: blk = b*256 + half*128 + qtile. 512 thr (8 waves); wave w handles keys
// [half*2048 + w*256, +256) = 4x64-key tiles. Block writes f32 partial sums (o_sh, l_sh)
// for its key-half; norm_kernel combines.
__global__ __launch_bounds__(512, 4)
void attn_mfma_kernel(const short* __restrict__ qT,
                      const short* __restrict__ kT,
                      const short* __restrict__ vT,
                      float* __restrict__ aoF, float* __restrict__ lF) {
    __shared__ unsigned p_lds[8][1024];   // per-wave [32 q][64 keys] bf16, swizzled
    __shared__ float o_sh[32][33];        // [d][q] plain-sum accumulator
    __shared__ float l_sh[32];

    int blk = blockIdx.x;
    int b = blk >> 8;
    int rem = blk & 255;
    int half = rem >> 7;
    int q0 = (rem & 127) << 5;
    int t = threadIdx.x, w = t >> 6, l = t & 63, lq = l & 15, h = l >> 4;

    for (int i = t; i < 32 * 33; i += 512) ((float*)o_sh)[i] = 0.f;
    if (t < 32) l_sh[t] = 0.f;

    const short* qTb = qT + ((size_t)b * P_ + q0) * HD_;
    const short* kTb = kT + (size_t)b * P_ * HD_;
    const short* vb  = vT + (size_t)b * HD_ * P_;

    short8 qf0 = *(const short8*)(qTb + lq * HD_ + h * 8);
    short8 qf1 = *(const short8*)(qTb + (16 + lq) * HD_ + h * 8);

    f32x4 o00 = {0.f,0.f,0.f,0.f}, o01 = {0.f,0.f,0.f,0.f};
    f32x4 o10 = {0.f,0.f,0.f,0.f}, o11 = {0.f,0.f,0.f,0.f};
    float lsum0 = 0.f, lsum1 = 0.f;
    unsigned* myp = &p_lds[w][0];
    int swz = (lq & 7) << 4;

    int key_base = half * 2048 + w * 256;
    short8 kf[4];
    {
        const short* kp = kTb + (size_t)(key_base + lq) * HD_ + h * 8;
        #pragma unroll
        for (int tt = 0; tt < 4; ++tt) kf[tt] = *(const short8*)(kp + tt * 16 * HD_);
    }
    __syncthreads();   // o_sh/l_sh zero visible before any ds_add

    for (int kt = 0; kt < 4; ++kt) {
        int key0 = key_base + kt * 64;
        // V loads for this tile (issue early; consumed after softmax chain)
        const short* vp = vb + (size_t)lq * P_ + key0 + h * 8;
        short8 vf0 = *(const short8*)(vp);
        short8 vf1 = *(const short8*)(vp + 32);
        short8 vf2 = *(const short8*)(vp + 16 * P_);
        short8 vf3 = *(const short8*)(vp + 16 * P_ + 32);

        // QK^T: 8 MFMAs (4 key-frags x 2 q-tiles)
        f32x4 st0[4], st1[4];
        __builtin_amdgcn_s_setprio(1);
        #pragma unroll
        for (int tt = 0; tt < 4; ++tt) {
            st0[tt] = __builtin_amdgcn_mfma_f32_16x16x32_bf16(kf[tt], qf0,
                          (f32x4){0.f,0.f,0.f,0.f}, 0, 0, 0);
            st1[tt] = __builtin_amdgcn_mfma_f32_16x16x32_bf16(kf[tt], qf1,
                          (f32x4){0.f,0.f,0.f,0.f}, 0, 0, 0);
        }
        __builtin_amdgcn_s_setprio(0);

        // prefetch next K tile
        if (kt < 3) {
            const short* kp = kTb + (size_t)(key0 + 64 + lq) * HD_ + h * 8;
            #pragma unroll
            for (int tt = 0; tt < 4; ++tt) kf[tt] = *(const short8*)(kp + tt * 16 * HD_);
        }

        // fixed-max softmax (exp2 domain), q-tile 0 then 1
        #pragma unroll
        for (int qt = 0; qt < 2; ++qt) {
            f32x4* st = qt ? st1 : st0;
            float e[16];
            #pragma unroll
            for (int tt = 0; tt < 4; ++tt)
                #pragma unroll
                for (int r = 0; r < 4; ++r) e[tt * 4 + r] = exp2a(st[tt][r]);
            float ls = 0.f;
            #pragma unroll
            for (int i = 0; i < 16; i += 4)
                ls += (e[i] + e[i + 1]) + (e[i + 2] + e[i + 3]);
            if (qt) lsum1 += ls; else lsum0 += ls;
            unsigned* row = myp + ((qt * 16 + lq) * 128 >> 2);
            #pragma unroll
            for (int tt = 0; tt < 4; ++tt) {
                int u0 = tt * 32 + h * 8;
                row[((u0 + 0) ^ swz) >> 2] = cvt_pk(e[tt * 4 + 0], e[tt * 4 + 1]);
                row[((u0 + 4) ^ swz) >> 2] = cvt_pk(e[tt * 4 + 2], e[tt * 4 + 3]);
            }
        }

        // PV B-frags from LDS (same-wave producer/consumer)
        short8 pb00, pb01, pb10, pb11;   // pb[qt][kh]
        __builtin_memcpy(&pb00, (const char*)myp + lq * 128        + ((h * 16 + 0)  ^ swz), 16);
        __builtin_memcpy(&pb01, (const char*)myp + lq * 128        + ((h * 16 + 64) ^ swz), 16);
        __builtin_memcpy(&pb10, (const char*)myp + (16 + lq) * 128 + ((h * 16 + 0)  ^ swz), 16);
        __builtin_memcpy(&pb11, (const char*)myp + (16 + lq) * 128 + ((h * 16 + 64) ^ swz), 16);

        __builtin_amdgcn_s_setprio(1);
        o00 = __builtin_amdgcn_mfma_f32_16x16x32_bf16(vf0, pb00, o00, 0, 0, 0);
        o00 = __builtin_amdgcn_mfma_f32_16x16x32_bf16(vf1, pb01, o00, 0, 0, 0);
        o01 = __builtin_amdgcn_mfma_f32_16x16x32_bf16(vf0, pb10, o01, 0, 0, 0);
        o01 = __builtin_amdgcn_mfma_f32_16x16x32_bf16(vf1, pb11, o01, 0, 0, 0);
        o10 = __builtin_amdgcn_mfma_f32_16x16x32_bf16(vf2, pb00, o10, 0, 0, 0);
        o10 = __builtin_amdgcn_mfma_f32_16x16x32_bf16(vf3, pb01, o10, 0, 0, 0);
        o11 = __builtin_amdgcn_mfma_f32_16x16x32_bf16(vf2, pb10, o11, 0, 0, 0);
        o11 = __builtin_amdgcn_mfma_f32_16x16x32_bf16(vf3, pb11, o11, 0, 0, 0);
        __builtin_amdgcn_s_setprio(0);
    }

    // cross-lane l reduction (per q)
    lsum0 += __shfl_xor(lsum0, 16); lsum0 += __shfl_xor(lsum0, 32);
    lsum1 += __shfl_xor(lsum1, 16); lsum1 += __shfl_xor(lsum1, 32);

    // plain-sum combine into shared accumulators
    #pragma unroll
    for (int r = 0; r < 4; ++r) {
        atomicAdd(&o_sh[h * 4 + r][lq],           o00[r]);
        atomicAdd(&o_sh[h * 4 + r][16 + lq],      o01[r]);
        atomicAdd(&o_sh[16 + h * 4 + r][lq],      o10[r]);
        atomicAdd(&o_sh[16 + h * 4 + r][16 + lq], o11[r]);
    }
    if (h == 0) {
        atomicAdd(&l_sh[lq],      lsum0);
        atomicAdd(&l_sh[16 + lq], lsum1);
    }
    __syncthreads();

    // write f32 partials for this key-half: 512 pair-writes = 32 q x 16 d-pairs
    {
        int qq = t >> 4;            // 0..31
        int d0 = (t & 15) * 2;      // 0..30
        float* dst = aoF + (size_t)half * B_ * P_ * HD_
                   + ((size_t)b * P_ + q0 + qq) * HD_ + d0;
        dst[0] = o_sh[d0][qq];
        dst[1] = o_sh[d0 + 1][qq];
    }
    if (t < 32)
        lF[(size_t)half * B_ * P_ + (size_t)b * P_ + q0 + t] = l_sh[t];
}

// ---- combine halves + normalize + pack bf16 into padded aoT. One thread per pixel.
__global__ __launch_bounds__(256)
void norm_kernel(const float* __restrict__ aoF, const float* __restrict__ lF,
                 short* __restrict__ aoT) {
    int pid = blockIdx.x * 256 + threadIdx.x;   // 0..16383
    int b = pid >> 12, p = pid & (P_ - 1);
    const float* a0 = aoF + ((size_t)b * P_ + p) * HD_;
    const float* a1 = a0 + (size_t)B_ * P_ * HD_;
    float ltot = lF[(size_t)b * P_ + p] + lF[(size_t)B_ * P_ + (size_t)b * P_ + p];
    float inv = 1.f / ltot;
    unsigned u[16];
    #pragma unroll
    for (int j = 0; j < 8; ++j) {
        f32x4 s0 = *(const f32x4*)(a0 + j * 4);
        f32x4 s1 = *(const f32x4*)(a1 + j * 4);
        f32x4 s = s0 + s1;
        u[2 * j]     = cvt_pk(s[0] * inv, s[1] * inv);
        u[2 * j + 1] = cvt_pk(s[2] * inv, s[3] * inv);
    }
    int hh = p >> 6, ww = p & 63;
    unsigned* dst = (unsigned*)(aoT + ((size_t)b * PADP + (hh + 1) * 66 + (ww + 1)) * HD_);
    #pragma unroll
    for (int j = 0; j < 16; ++j) dst[j] = u[j];
}

// ---- Conv implicit GEMM: 512 threads (8 waves), wave w: co [w*48, w*48+48), 32-pixel tile
__global__ __launch_bounds__(512)
void conv_mfma_kernel(const short* __restrict__ Wbc,
                      const short* __restrict__ aoT,
                      const float* __restrict__ bout,
                      const float* __restrict__ x,
                      float* __restrict__ out) {
    int blk = blockIdx.x;
    int b = blk >> 7;
    int p0 = (blk & 127) << 5;
    int t = threadIdx.x;
    int w = t >> 6, l = t & 63, lq = l & 15, h = l >> 4;
    int co0 = w * 48;

    const short* aob = aoT + (size_t)b * PADP * HD_;
    const short* bptr[2];
    #pragma unroll
    for (int n = 0; n < 2; ++n) {
        int p = p0 + n * 16 + lq;
        int hh = p >> 6, ww = p & 63;
        bptr[n] = aob + (size_t)(hh * 66 + ww) * HD_ + h * 8;
    }
    const short* aptr = Wbc + (size_t)(co0 + lq) * 32 + h * 8;

    f32x4 acc[3][2];
    #pragma unroll
    for (int m = 0; m < 3; ++m)
        #pragma unroll
        for (int n = 0; n < 2; ++n) acc[m][n] = (f32x4){0.f, 0.f, 0.f, 0.f};

    short8 Bf0 = *(const short8*)(bptr[0]);
    short8 Bf1 = *(const short8*)(bptr[1]);
    #pragma unroll
    for (int kk = 0; kk < 9; ++kk) {
        short8 nB0, nB1;
        if (kk < 8) {
            int ky = (kk + 1) / 3, kx = (kk + 1) % 3;
            nB0 = *(const short8*)(bptr[0] + (ky * 66 + kx) * HD_);
            nB1 = *(const short8*)(bptr[1] + (ky * 66 + kx) * HD_);
        } else { nB0 = Bf0; nB1 = Bf1; }
        #pragma unroll
        for (int m = 0; m < 3; ++m) {
            short8 Af = *(const short8*)(aptr + kk * 12288 + m * 512);
            acc[m][0] = __builtin_amdgcn_mfma_f32_16x16x32_bf16(Af, Bf0, acc[m][0], 0, 0, 0);
            acc[m][1] = __builtin_amdgcn_mfma_f32_16x16x32_bf16(Af, Bf1, acc[m][1], 0, 0, 0);
        }
        Bf0 = nB0; Bf1 = nB1;
    }

    #pragma unroll
    for (int m = 0; m < 3; ++m) {
        #pragma unroll
        for (int r = 0; r < 4; ++r) {
            int co = co0 + m * 16 + h * 4 + r;
            float bias = bout[co];
            #pragma unroll
            for (int n = 0; n < 2; ++n) {
                int p = p0 + n * 16 + lq;
                size_t idx = ((size_t)b * C_ + co) * P_ + p;
                out[idx] = acc[m][n][r] + bias + x[idx];
            }
        }
    }
}

extern "C" void kernel_launch(void* const* d_in, const int* in_sizes, int n_in,
                              void* d_out, int out_size, void* d_ws, size_t ws_size,
                              hipStream_t stream) {
    const float* x    = (const float*)d_in[0];
    const float* xe   = (const float*)d_in[1];
    const float* Wq   = (const float*)d_in[2];
    const float* Wkv  = (const float*)d_in[3];
    const float* Wout = (const float*)d_in[4];
    const float* bout = (const float*)d_in[5];
    float* out = (float*)d_out;

    short* qT    = (short*)d_ws;                      // B*P*32 bf16
    short* kT    = qT  + (size_t)B_ * P_ * HD_;       // B*P*32 bf16
    short* vT    = kT  + (size_t)B_ * P_ * HD_;       // B*32*P bf16
    short* aoT   = vT  + (size_t)B_ * P_ * HD_;       // B*PADP*32 bf16
    float* aoF   = (float*)(aoT + (size_t)B_ * PADP * HD_); // 2*B*P*32 f32
    float* lF    = aoF + (size_t)2 * B_ * P_ * HD_;   // 2*B*P f32
    short* Wball = (short*)(lF + (size_t)2 * B_ * P_); // 96*384 bf16
    short* Wbc   = Wball + 96 * C_;                   // 9*384*32 bf16

    repack_kernel<<<576, 256, 0, stream>>>(Wq, Wkv, Wout, Wball, Wbc, (unsigned*)aoT);
    proj_kernel<<<dim3(128, B_), 768, 0, stream>>>(x, xe, Wball, qT, kT, vT);
    attn_mfma_kernel<<<B_ * 256, 512, 0, stream>>>(qT, kT, vT, aoF, lF);
    norm_kernel<<<64, 256, 0, stream>>>(aoF, lF, aoT);
    conv_mfma_kernel<<<B_ * 128, 512, 0, stream>>>(Wbc, aoT, bout, x, out);
}

// Round 13
// 89.779 us; speedup vs baseline: 1.3120x; 1.3120x over previous
//
#include <hip/hip_runtime.h>
#include <hip/hip_bf16.h>
#include <math.h>

// B=4, C=384, H=W=Y=X=64, n_head=1, hd=32, P=4096
#define B_   4
#define C_   384
#define HD_  32
#define P_   4096
#define PADP 4356   // 66*66 padded pixel space
#define QSC_ 0.2550889266f   // (1/sqrt(32)) * log2(e), folded into Wq -> exp2 domain

typedef __attribute__((ext_vector_type(4))) float f32x4;
typedef __attribute__((ext_vector_type(8))) short short8;

static __device__ inline unsigned cvt_pk(float lo, float hi) {
    unsigned r;
    asm("v_cvt_pk_bf16_f32 %0, %1, %2" : "=v"(r) : "v"(lo), "v"(hi));
    return r;
}
static __device__ inline float exp2a(float x) {
    float r;
    asm("v_exp_f32 %0, %1" : "=v"(r) : "v"(x));
    return r;
}
static __device__ inline short bf16_bits(float a) {
    __hip_bfloat16 x = __float2bfloat16(a);
    return *reinterpret_cast<short*>(&x);
}

// ---- merged: weight repack + aoT border zero.
__global__ void repack_kernel(const float* __restrict__ Wq,
                              const float* __restrict__ Wkv,
                              const float* __restrict__ Wout,
                              short* __restrict__ Wball,
                              short* __restrict__ Wbc,
                              unsigned* __restrict__ aoT32) {
    int idx = blockIdx.x * 256 + threadIdx.x;
    if (idx < B_ * 260 * 16) {   // zero the 260 border pixels x 16 dwords
        int j = idx & 15;
        int p = (idx >> 4) % 260;
        int b = idx / (260 * 16);
        int hh, ww;
        if (p < 66)       { hh = 0;  ww = p; }
        else if (p < 132) { hh = 65; ww = p - 66; }
        else { int i = p - 132; hh = 1 + (i >> 1); ww = (i & 1) * 65; }
        aoT32[((size_t)b * PADP + hh * 66 + ww) * 16 + j] = 0;
    }
    if (idx < 96 * C_) {
        int r = idx / C_, c = idx % C_;
        float v = (r < 32) ? Wq[r * C_ + c] * QSC_ : Wkv[(r - 32) * C_ + c];
        Wball[idx] = bf16_bits(v);
    }
    int j = idx - 96 * C_;
    if (j >= 0 && j < 9 * 384 * 32) {
        int ci = j & 31;
        int co = (j >> 5) % 384;
        int kk = j / (384 * 32);
        int ky = kk / 3, kx = kk % 3;
        Wbc[j] = bf16_bits(Wout[((co * 32 + ci) * 3 + ky) * 3 + kx]);
    }
}

// ---- unified q/k/v projection from f32 inputs.
// mt 0,1: q -> qT[b][p][32]; mt 2,3: k -> kT[b][p][32]; mt 4,5: v -> vT[b][32][P]
__global__ __launch_bounds__(768)
void proj_kernel(const float* __restrict__ x, const float* __restrict__ xe,
                 const short* __restrict__ Wball,
                 short* __restrict__ qT, short* __restrict__ kT,
                 short* __restrict__ vT) {
    int b = blockIdx.y;
    int p0 = blockIdx.x << 5;
    int t = threadIdx.x, w = t >> 6, l = t & 63, lq = l & 15, h = l >> 4;
    int mt = w >> 1, pg = w & 1;
    int p = p0 + pg * 16 + lq;
    const float* in = (mt < 2) ? x : xe;
    const float* xb = in + (size_t)b * C_ * P_ + p;
    const short* Ap = Wball + (size_t)(mt * 16 + lq) * C_ + h * 8;
    f32x4 acc = {0.f, 0.f, 0.f, 0.f};
    for (int ks = 0; ks < 12; ++ks) {
        float xv[8];
        #pragma unroll
        for (int jj = 0; jj < 8; ++jj)
            xv[jj] = xb[(size_t)(ks * 32 + h * 8 + jj) * P_];
        unsigned u[4];
        #pragma unroll
        for (int jj = 0; jj < 4; ++jj) u[jj] = cvt_pk(xv[2 * jj], xv[2 * jj + 1]);
        short8 bf;
        __builtin_memcpy(&bf, u, 16);
        short8 af = *(const short8*)(Ap + ks * 32);
        acc = __builtin_amdgcn_mfma_f32_16x16x32_bf16(af, bf, acc, 0, 0, 0);
    }
    if (mt < 4) {
        short* dst = (mt < 2) ? qT : kT;
        int d = (mt & 1) * 16 + h * 4;
        uint2 u;
        u.x = cvt_pk(acc[0], acc[1]);
        u.y = cvt_pk(acc[2], acc[3]);
        *(uint2*)(dst + ((size_t)b * P_ + p) * HD_ + d) = u;
    } else {
        int d = (mt - 4) * 16 + h * 4;
        #pragma unroll
        for (int r = 0; r < 4; ++r)
            vT[((size_t)b * HD_ + d + r) * P_ + p] = bf16_bits(acc[r]);
    }
}

// ---- Flash attention, MFMA, FIXED-MAX softmax (exp2 domain, scale in Wq).
// grid B_*256 (16-q tiles), 256 thr (4 waves); wave w: keys [w*1024, +1024), 16x64-key tiles.
// XCD-aware block swizzle: each XCD works one batch -> K+V (2MB) stays L2-resident.
__global__ __launch_bounds__(256, 4)
void attn_mfma_kernel(const short* __restrict__ qT,
                      const short* __restrict__ kT,
                      const short* __restrict__ vT,
                      short* __restrict__ aoT) {
    __shared__ unsigned p_lds[4][512];   // per-wave [16 q][64 keys] bf16, swizzled
    __shared__ float o_lds[4][32][16];
    __shared__ float l_lds[4][16];

    // T1 bijective XCD swizzle: 1024 blocks, 8 XCDs -> XCD k gets contiguous
    // chunk [k*128, (k+1)*128) = one batch's blocks (2 XCDs per batch).
    int bid = blockIdx.x;
    int blk = (bid & 7) * 128 + (bid >> 3);
    int b = blk >> 8;
    int q0 = (blk & 255) << 4;
    int t = threadIdx.x, w = t >> 6, l = t & 63, lq = l & 15, h = l >> 4;

    const short* qTb = qT + ((size_t)b * P_ + q0) * HD_;
    const short* kTb = kT + (size_t)b * P_ * HD_;
    const short* vb  = vT + (size_t)b * HD_ * P_;

    short8 qf = *(const short8*)(qTb + lq * HD_ + h * 8);

    f32x4 o0 = {0.f, 0.f, 0.f, 0.f}, o1 = {0.f, 0.f, 0.f, 0.f};
    float lsum = 0.f;
    unsigned* myp = &p_lds[w][0];
    int swz = (lq & 7) << 4;

    int key_base = w * 1024;
    short8 kf[4], vf[4];
    {
        const short* kp = kTb + (size_t)(key_base + lq) * HD_ + h * 8;
        #pragma unroll
        for (int tt = 0; tt < 4; ++tt) kf[tt] = *(const short8*)(kp + tt * 16 * HD_);
        const short* vp = vb + (size_t)lq * P_ + key_base + h * 8;
        vf[0] = *(const short8*)(vp);
        vf[1] = *(const short8*)(vp + 32);
        vf[2] = *(const short8*)(vp + 16 * P_);
        vf[3] = *(const short8*)(vp + 16 * P_ + 32);
    }

    for (int kt = 0; kt < 16; ++kt) {
        // prefetch next K/V tile
        short8 nk[4], nv[4];
        if (kt < 15) {
            int nxt = key_base + (kt + 1) * 64;
            const short* kp = kTb + (size_t)(nxt + lq) * HD_ + h * 8;
            #pragma unroll
            for (int tt = 0; tt < 4; ++tt) nk[tt] = *(const short8*)(kp + tt * 16 * HD_);
            const short* vp = vb + (size_t)lq * P_ + nxt + h * 8;
            nv[0] = *(const short8*)(vp);
            nv[1] = *(const short8*)(vp + 32);
            nv[2] = *(const short8*)(vp + 16 * P_);
            nv[3] = *(const short8*)(vp + 16 * P_ + 32);
        } else {
            #pragma unroll
            for (int tt = 0; tt < 4; ++tt) { nk[tt] = kf[tt]; nv[tt] = vf[tt]; }
        }

        f32x4 st[4];
        __builtin_amdgcn_s_setprio(1);
        #pragma unroll
        for (int tt = 0; tt < 4; ++tt)
            st[tt] = __builtin_amdgcn_mfma_f32_16x16x32_bf16(kf[tt], qf,
                         (f32x4){0.f, 0.f, 0.f, 0.f}, 0, 0, 0);
        __builtin_amdgcn_s_setprio(0);

        // fixed-max softmax: e = exp2(s) directly (scores bounded ~|s|<8 by construction)
        float e[16];
        #pragma unroll
        for (int tt = 0; tt < 4; ++tt)
            #pragma unroll
            for (int r = 0; r < 4; ++r) e[tt * 4 + r] = exp2a(st[tt][r]);
        float ls = 0.f;
        #pragma unroll
        for (int i = 0; i < 16; i += 4)
            ls += (e[i] + e[i + 1]) + (e[i + 2] + e[i + 3]);
        lsum += ls;

        #pragma unroll
        for (int tt = 0; tt < 4; ++tt) {
            int u0 = tt * 32 + h * 8;
            myp[(lq * 128 + ((u0 + 0) ^ swz)) >> 2] = cvt_pk(e[tt * 4 + 0], e[tt * 4 + 1]);
            myp[(lq * 128 + ((u0 + 4) ^ swz)) >> 2] = cvt_pk(e[tt * 4 + 2], e[tt * 4 + 3]);
        }
        short8 pb0, pb1;
        __builtin_memcpy(&pb0, (const char*)myp + lq * 128 + ((h * 16 + 0)  ^ swz), 16);
        __builtin_memcpy(&pb1, (const char*)myp + lq * 128 + ((h * 16 + 64) ^ swz), 16);

        __builtin_amdgcn_s_setprio(1);
        o0 = __builtin_amdgcn_mfma_f32_16x16x32_bf16(vf[0], pb0, o0, 0, 0, 0);
        o0 = __builtin_amdgcn_mfma_f32_16x16x32_bf16(vf[1], pb1, o0, 0, 0, 0);
        o1 = __builtin_amdgcn_mfma_f32_16x16x32_bf16(vf[2], pb0, o1, 0, 0, 0);
        o1 = __builtin_amdgcn_mfma_f32_16x16x32_bf16(vf[3], pb1, o1, 0, 0, 0);
        __builtin_amdgcn_s_setprio(0);

        #pragma unroll
        for (int tt = 0; tt < 4; ++tt) { kf[tt] = nk[tt]; vf[tt] = nv[tt]; }
    }

    // deferred cross-lane l reduction (only 2 shuffles per whole kernel)
    lsum += __shfl_xor(lsum, 16);
    lsum += __shfl_xor(lsum, 32);

    #pragma unroll
    for (int r = 0; r < 4; ++r) {
        o_lds[w][h * 4 + r][lq]      = o0[r];
        o_lds[w][16 + h * 4 + r][lq] = o1[r];
    }
    if (h == 0) l_lds[w][lq] = lsum;
    __syncthreads();

    // combine across 4 waves: plain sums (no max state). 512 outputs.
    {
        int qq = t >> 4;
        int d0 = (t & 15) * 2;
        float denom = l_lds[0][qq] + l_lds[1][qq] + l_lds[2][qq] + l_lds[3][qq];
        float v0 = 0.f, v1 = 0.f;
        #pragma unroll
        for (int ww = 0; ww < 4; ++ww) {
            v0 += o_lds[ww][d0][qq];
            v1 += o_lds[ww][d0 + 1][qq];
        }
        float inv = 1.f / denom;
        int p = q0 + qq;
        int hh = p >> 6, ww2 = p & 63;
        unsigned* dst = (unsigned*)(aoT +
            ((size_t)b * PADP + (hh + 1) * 66 + (ww2 + 1)) * HD_ + d0);
        *dst = cvt_pk(v0 * inv, v1 * inv);
    }
}

// ---- Conv implicit GEMM: 512 threads (8 waves), wave w: co [w*48, w*48+48), 32-pixel tile
__global__ __launch_bounds__(512)
void conv_mfma_kernel(const short* __restrict__ Wbc,
                      const short* __restrict__ aoT,
                      const float* __restrict__ bout,
                      const float* __restrict__ x,
                      float* __restrict__ out) {
    int blk = blockIdx.x;
    int b = blk >> 7;
    int p0 = (blk & 127) << 5;
    int t = threadIdx.x;
    int w = t >> 6, l = t & 63, lq = l & 15, h = l >> 4;
    int co0 = w * 48;

    const short* aob = aoT + (size_t)b * PADP * HD_;
    const short* bptr[2];
    #pragma unroll
    for (int n = 0; n < 2; ++n) {
        int p = p0 + n * 16 + lq;
        int hh = p >> 6, ww = p & 63;
        bptr[n] = aob + (size_t)(hh * 66 + ww) * HD_ + h * 8;
    }
    const short* aptr = Wbc + (size_t)(co0 + lq) * 32 + h * 8;

    f32x4 acc[3][2];
    #pragma unroll
    for (int m = 0; m < 3; ++m)
        #pragma unroll
        for (int n = 0; n < 2; ++n) acc[m][n] = (f32x4){0.f, 0.f, 0.f, 0.f};

    short8 Bf0 = *(const short8*)(bptr[0]);
    short8 Bf1 = *(const short8*)(bptr[1]);
    #pragma unroll
    for (int kk = 0; kk < 9; ++kk) {
        short8 nB0, nB1;
        if (kk < 8) {
            int ky = (kk + 1) / 3, kx = (kk + 1) % 3;
            nB0 = *(const short8*)(bptr[0] + (ky * 66 + kx) * HD_);
            nB1 = *(const short8*)(bptr[1] + (ky * 66 + kx) * HD_);
        } else { nB0 = Bf0; nB1 = Bf1; }
        #pragma unroll
        for (int m = 0; m < 3; ++m) {
            short8 Af = *(const short8*)(aptr + kk * 12288 + m * 512);
            acc[m][0] = __builtin_amdgcn_mfma_f32_16x16x32_bf16(Af, Bf0, acc[m][0], 0, 0, 0);
            acc[m][1] = __builtin_amdgcn_mfma_f32_16x16x32_bf16(Af, Bf1, acc[m][1], 0, 0, 0);
        }
        Bf0 = nB0; Bf1 = nB1;
    }

    #pragma unroll
    for (int m = 0; m < 3; ++m) {
        #pragma unroll
        for (int r = 0; r < 4; ++r) {
            int co = co0 + m * 16 + h * 4 + r;
            float bias = bout[co];
            #pragma unroll
            for (int n = 0; n < 2; ++n) {
                int p = p0 + n * 16 + lq;
                size_t idx = ((size_t)b * C_ + co) * P_ + p;
                out[idx] = acc[m][n][r] + bias + x[idx];
            }
        }
    }
}

extern "C" void kernel_launch(void* const* d_in, const int* in_sizes, int n_in,
                              void* d_out, int out_size, void* d_ws, size_t ws_size,
                              hipStream_t stream) {
    const float* x    = (const float*)d_in[0];
    const float* xe   = (const float*)d_in[1];
    const float* Wq   = (const float*)d_in[2];
    const float* Wkv  = (const float*)d_in[3];
    const float* Wout = (const float*)d_in[4];
    const float* bout = (const float*)d_in[5];
    float* out = (float*)d_out;

    short* qT    = (short*)d_ws;                      // B*P*32
    short* kT    = qT  + (size_t)B_ * P_ * HD_;       // B*P*32
    short* vT    = kT  + (size_t)B_ * P_ * HD_;       // B*32*P
    short* aoT   = vT  + (size_t)B_ * P_ * HD_;       // B*PADP*32
    short* Wball = aoT + (size_t)B_ * PADP * HD_;     // 96*384
    short* Wbc   = Wball + 96 * C_;                   // 9*384*32

    repack_kernel<<<576, 256, 0, stream>>>(Wq, Wkv, Wout, Wball, Wbc, (unsigned*)aoT);
    proj_kernel<<<dim3(128, B_), 768, 0, stream>>>(x, xe, Wball, qT, kT, vT);
    attn_mfma_kernel<<<B_ * 256, 256, 0, stream>>>(qT, kT, vT, aoT);
    conv_mfma_kernel<<<B_ * 128, 512, 0, stream>>>(Wbc, aoT, bout, x, out);
}